// Round 8
// baseline (214.203 us; speedup 1.0000x reference)
//
#include <hip/hip_runtime.h>
#include <hip/hip_fp16.h>
#include <math.h>

#define IN_CH 128
#define G4    512   // 4*IN
#define K1    256   // 2*IN

__device__ __forceinline__ float sigmoidf_(float v){ return 1.f/(1.f + expf(-v)); }

__device__ __forceinline__ float dot4_(float4 a, float4 b){
  return a.x*b.x + a.y*b.y + a.z*b.z + a.w*b.w;
}

// All-reduce-sum over each 8-lane group: 3 pure-DPP stages (VALU speed, no LDS pipe).
__device__ __forceinline__ float reduce8_(float v){
  int t;
  t = __builtin_amdgcn_update_dpp(0, __float_as_int(v), 0xB1, 0xF, 0xF, true);   // quad_perm xor1
  v += __int_as_float(t);
  t = __builtin_amdgcn_update_dpp(0, __float_as_int(v), 0x4E, 0xF, 0xF, true);   // quad_perm xor2
  v += __int_as_float(t);
  t = __builtin_amdgcn_update_dpp(0, __float_as_int(v), 0x141, 0xF, 0xF, true);  // row_half_mirror = xor4
  v += __int_as_float(t);
  return v;
}

__device__ __forceinline__ float swz8_(float v){
  return __int_as_float(__builtin_amdgcn_ds_swizzle(__float_as_int(v), 0x201F)); // lane ^ 8
}
__device__ __forceinline__ float swz16_(float v){
  return __int_as_float(__builtin_amdgcn_ds_swizzle(__float_as_int(v), 0x401F)); // lane ^ 16
}

__device__ __forceinline__ unsigned int packh2_(float a, float b){
  __half2 h = __floats2half2_rn(a, b);
  return *reinterpret_cast<unsigned int*>(&h);
}

__device__ __forceinline__ void h8_to_f_(uint4 u, float4& lo, float4& hi){
  const __half2* hp = reinterpret_cast<const __half2*>(&u);
  float2 a = __half22float2(hp[0]);
  float2 b = __half22float2(hp[1]);
  float2 c = __half22float2(hp[2]);
  float2 d = __half22float2(hp[3]);
  lo = make_float4(a.x, a.y, b.x, b.y);
  hi = make_float4(c.x, c.y, d.x, d.y);
}

// Prologue: transpose weights + segment bounds + step-0 LSTM collapse (bias-only).
__global__ void prologue_kernel(const float* __restrict__ w_ih, const float* __restrict__ w_hh,
                                float* __restrict__ wTih, float* __restrict__ wThh,
                                const int* __restrict__ batch, int N, int B, int* __restrict__ segs,
                                const float* __restrict__ b_ih, const float* __restrict__ b_hh,
                                float* __restrict__ h, float* __restrict__ c, float* __restrict__ qstar){
  int blk = blockIdx.x;
  if (blk < 512){                       // transpose: idx over G4*K1 = 131072
    int idx = blk*256 + threadIdx.x;
    { int g = idx / K1; int k = idx - g*K1; wTih[k*G4 + g] = w_ih[idx]; }
    if (idx < G4*IN_CH){ int g = idx / IN_CH; int k = idx - g*IN_CH; wThh[k*G4 + g] = w_hh[idx]; }
  } else if (blk < 517){                // seg bounds: b in [0, B]
    int b = (blk - 512)*256 + threadIdx.x;
    if (b > B) return;
    if (b == B){ segs[B] = N; return; }
    int lo = 0, hi = N;
    while (lo < hi){ int mid = (lo + hi) >> 1; if (batch[mid] < b) lo = mid + 1; else hi = mid; }
    segs[b] = lo;
  } else {                              // init0: idx over B*IN_CH = 131072
    int idx = (blk - 517)*256 + threadIdx.x;
    if (idx >= B*IN_CH) return;
    int b = idx >> 7, ch = idx & 127;
    float iv = sigmoidf_(b_ih[ch]           + b_hh[ch]);
    float gv = tanhf    (b_ih[2*IN_CH + ch] + b_hh[2*IN_CH + ch]);
    float ov = sigmoidf_(b_ih[3*IN_CH + ch] + b_hh[3*IN_CH + ch]);
    float cv = iv*gv;           // f*c_prev = 0
    float hv = ov*tanhf(cv);
    c[idx] = cv; h[idx] = hv;
    qstar[b*K1 + ch] = hv;
  }
}

// Fused LSTM step (steps 1,2): gates in LDS, then cell update + q-half write.
__global__ __launch_bounds__(512) void lstm_fused_kernel(
    const float* __restrict__ qstar_in, float* __restrict__ h, float* __restrict__ c,
    const float* __restrict__ wTih, const float* __restrict__ wThh,
    const float* __restrict__ b_ih, const float* __restrict__ b_hh,
    float* __restrict__ qstar_out){
  int g    = threadIdx.x;      // 0..511
  int row0 = blockIdx.x*8;
  __shared__ float qs[8][K1];
  __shared__ float hs[8][IN_CH];
  __shared__ float gs[8][G4];
  for (int t = g; t < 8*K1; t += 512){ int r = t >> 8; int k = t & 255; qs[r][k] = qstar_in[(row0+r)*K1 + k]; }
  for (int t = g; t < 8*IN_CH; t += 512){ int r = t >> 7; int k = t & 127; hs[r][k] = h[(row0+r)*IN_CH + k]; }
  __syncthreads();
  float bias = b_ih[g] + b_hh[g];
  float acc[8];
#pragma unroll
  for (int r = 0; r < 8; ++r) acc[r] = bias;
  for (int k4 = 0; k4 < K1/4; ++k4){
    float w0 = wTih[(4*k4+0)*G4 + g];
    float w1 = wTih[(4*k4+1)*G4 + g];
    float w2 = wTih[(4*k4+2)*G4 + g];
    float w3 = wTih[(4*k4+3)*G4 + g];
#pragma unroll
    for (int r = 0; r < 8; ++r){
      float4 q = *reinterpret_cast<const float4*>(&qs[r][4*k4]);
      acc[r] += q.x*w0 + q.y*w1 + q.z*w2 + q.w*w3;
    }
  }
  for (int k4 = 0; k4 < IN_CH/4; ++k4){
    float w0 = wThh[(4*k4+0)*G4 + g];
    float w1 = wThh[(4*k4+1)*G4 + g];
    float w2 = wThh[(4*k4+2)*G4 + g];
    float w3 = wThh[(4*k4+3)*G4 + g];
#pragma unroll
    for (int r = 0; r < 8; ++r){
      float4 hv = *reinterpret_cast<const float4*>(&hs[r][4*k4]);
      acc[r] += hv.x*w0 + hv.y*w1 + hv.z*w2 + hv.w*w3;
    }
  }
#pragma unroll
  for (int r = 0; r < 8; ++r) gs[r][g] = acc[r];
  __syncthreads();
  for (int t = g; t < 8*IN_CH; t += 512){
    int r = t >> 7, ch = t & 127;
    int idx = (row0+r)*IN_CH + ch;
    float iv = sigmoidf_(gs[r][ch]);
    float fv = sigmoidf_(gs[r][IN_CH + ch]);
    float gv = tanhf(gs[r][2*IN_CH + ch]);
    float ov = sigmoidf_(gs[r][3*IN_CH + ch]);
    float cv = fv*c[idx] + iv*gv;
    float hv = ov*tanhf(cv);
    c[idx] = cv; h[idx] = hv;
    qstar_out[(row0+r)*K1 + ch] = hv;
  }
}

// Merge/epilogue macro shared by both attn kernels.
#define MERGE_STAGE(GET)                                                        \
  {                                                                             \
    float mo = GET(m), dd = GET(d);                                             \
    float4 sa, sb, sc, sd;                                                      \
    sa.x = GET(ra.x); sa.y = GET(ra.y); sa.z = GET(ra.z); sa.w = GET(ra.w);     \
    sb.x = GET(rb.x); sb.y = GET(rb.y); sb.z = GET(rb.z); sb.w = GET(rb.w);     \
    sc.x = GET(rc.x); sc.y = GET(rc.y); sc.z = GET(rc.z); sc.w = GET(rc.w);     \
    sd.x = GET(rd.x); sd.y = GET(rd.y); sd.z = GET(rd.z); sd.w = GET(rd.w);     \
    float mn = fmaxf(m, mo);                                                    \
    float c1 = (mn == -INFINITY) ? 0.f : __expf(m - mn);                        \
    float c2 = (mn == -INFINITY) ? 0.f : __expf(mo - mn);                       \
    d = d*c1 + dd*c2;                                                           \
    ra.x = ra.x*c1 + sa.x*c2; ra.y = ra.y*c1 + sa.y*c2;                         \
    ra.z = ra.z*c1 + sa.z*c2; ra.w = ra.w*c1 + sa.w*c2;                         \
    rb.x = rb.x*c1 + sb.x*c2; rb.y = rb.y*c1 + sb.y*c2;                         \
    rb.z = rb.z*c1 + sb.z*c2; rb.w = rb.w*c1 + sb.w*c2;                         \
    rc.x = rc.x*c1 + sc.x*c2; rc.y = rc.y*c1 + sc.y*c2;                         \
    rc.z = rc.z*c1 + sc.z*c2; rc.w = rc.w*c1 + sc.w*c2;                         \
    rd.x = rd.x*c1 + sd.x*c2; rd.y = rd.y*c1 + sd.y*c2;                         \
    rd.z = rd.z*c1 + sd.z*c2; rd.w = rd.w*c1 + sd.w*c2;                         \
    m = mn;                                                                     \
  }
#define SHFL32(v) __shfl_xor((v), 32)

// Step-0 attention: reads f32 x, also emits fp16 copy of x for steps 1,2.
// Channels per lane: {4*l8, 32+4*l8, 64+4*l8, 96+4*l8} (+0..3 each).
__global__ __launch_bounds__(256) void attn_first_kernel(const float* __restrict__ x,
    __half* __restrict__ xh, float* __restrict__ qstar, const int* __restrict__ segs){
  int b = blockIdx.x;
  int s = segs[b], ce = segs[b+1];
  int jmax = (ce > 0) ? (ce - 1) : 0;
  int tid = threadIdx.x;
  int wave = tid >> 6, lane = tid & 63;
  int grp = lane >> 3, l8 = lane & 7;
  int sid = wave*8 + grp;
  const float4 z4 = make_float4(0.f,0.f,0.f,0.f);
  const float4* x4 = reinterpret_cast<const float4*>(x);
  const float4* q4 = reinterpret_cast<const float4*>(&qstar[(size_t)b*K1]);
  float4 q0 = q4[l8], q1 = q4[8 + l8], q2 = q4[16 + l8], q3 = q4[24 + l8];

  float m = -INFINITY, d = 0.f;
  float4 ra = z4, rb = z4, rc = z4, rd = z4;

  int j = s + sid;
  float4 A0, A1, A2, A3, B0, B1, B2, B3;
  {
    int jc0 = (j      < ce) ? j      : jmax;
    int jc1 = (j + 32 < ce) ? j + 32 : jmax;
    const float4* r0 = x4 + (size_t)jc0*(IN_CH/4);
    const float4* r1 = x4 + (size_t)jc1*(IN_CH/4);
    A0 = r0[l8]; A1 = r0[8 + l8]; A2 = r0[16 + l8]; A3 = r0[24 + l8];
    B0 = r1[l8]; B1 = r1[8 + l8]; B2 = r1[16 + l8]; B3 = r1[24 + l8];
  }
  for (; j < ce; j += 32){
    int jn = j + 64;
    int jc = (jn < ce) ? jn : jmax;
    const float4* rp = x4 + (size_t)jc*(IN_CH/4);
    float4 C0 = rp[l8], C1 = rp[8 + l8], C2 = rp[16 + l8], C3 = rp[24 + l8];

    // emit fp16 copy of this row (each row processed exactly once grid-wide)
    uint2* hrow = reinterpret_cast<uint2*>(xh + (size_t)j*IN_CH);
    hrow[     l8] = make_uint2(packh2_(A0.x, A0.y), packh2_(A0.z, A0.w));
    hrow[ 8 + l8] = make_uint2(packh2_(A1.x, A1.y), packh2_(A1.z, A1.w));
    hrow[16 + l8] = make_uint2(packh2_(A2.x, A2.y), packh2_(A2.z, A2.w));
    hrow[24 + l8] = make_uint2(packh2_(A3.x, A3.y), packh2_(A3.z, A3.w));

    float e = dot4_(A0, q0) + dot4_(A1, q1) + dot4_(A2, q2) + dot4_(A3, q3);
    e = reduce8_(e);
    if (e > m){
      float corr = __expf(m - e);
      d *= corr;
      ra.x *= corr; ra.y *= corr; ra.z *= corr; ra.w *= corr;
      rb.x *= corr; rb.y *= corr; rb.z *= corr; rb.w *= corr;
      rc.x *= corr; rc.y *= corr; rc.z *= corr; rc.w *= corr;
      rd.x *= corr; rd.y *= corr; rd.z *= corr; rd.w *= corr;
      m = e;
    }
    float p = __expf(e - m);
    d += p;
    ra.x += p*A0.x; ra.y += p*A0.y; ra.z += p*A0.z; ra.w += p*A0.w;
    rb.x += p*A1.x; rb.y += p*A1.y; rb.z += p*A1.z; rb.w += p*A1.w;
    rc.x += p*A2.x; rc.y += p*A2.y; rc.z += p*A2.z; rc.w += p*A2.w;
    rd.x += p*A3.x; rd.y += p*A3.y; rd.z += p*A3.z; rd.w += p*A3.w;
    A0 = B0; A1 = B1; A2 = B2; A3 = B3;
    B0 = C0; B1 = C1; B2 = C2; B3 = C3;
  }
  MERGE_STAGE(swz8_)
  MERGE_STAGE(swz16_)
  MERGE_STAGE(SHFL32)

  __shared__ float mbuf[4], dbuf[4];
  __shared__ float rbuf[4][IN_CH];
  if (lane < 8){
    *reinterpret_cast<float4*>(&rbuf[wave][ 0 + lane*4]) = ra;
    *reinterpret_cast<float4*>(&rbuf[wave][32 + lane*4]) = rb;
    *reinterpret_cast<float4*>(&rbuf[wave][64 + lane*4]) = rc;
    *reinterpret_cast<float4*>(&rbuf[wave][96 + lane*4]) = rd;
    if (lane == 0){ mbuf[wave] = m; dbuf[wave] = d; }
  }
  __syncthreads();
  if (tid < IN_CH){
    float M = fmaxf(fmaxf(mbuf[0], mbuf[1]), fmaxf(mbuf[2], mbuf[3]));
    float f0 = (M == -INFINITY) ? 0.f : __expf(mbuf[0] - M);
    float f1 = (M == -INFINITY) ? 0.f : __expf(mbuf[1] - M);
    float f2 = (M == -INFINITY) ? 0.f : __expf(mbuf[2] - M);
    float f3 = (M == -INFINITY) ? 0.f : __expf(mbuf[3] - M);
    float R = rbuf[0][tid]*f0 + rbuf[1][tid]*f1 + rbuf[2][tid]*f2 + rbuf[3][tid]*f3;
    float D = dbuf[0]*f0 + dbuf[1]*f1 + dbuf[2]*f2 + dbuf[3]*f3;
    qstar[(size_t)b*K1 + IN_CH + tid] = (D > 0.f) ? R/D : 0.f;
  }
}

// Steps 1,2 attention: reads fp16 x (half the bytes).
// Channels per lane: {l8*8..+7, 64+l8*8..+7} (two uint4 = 8 halves each).
__global__ __launch_bounds__(256) void attn_half_kernel(const __half* __restrict__ xh,
    float* __restrict__ qstar, const int* __restrict__ segs){
  int b = blockIdx.x;
  int s = segs[b], ce = segs[b+1];
  int jmax = (ce > 0) ? (ce - 1) : 0;
  int tid = threadIdx.x;
  int wave = tid >> 6, lane = tid & 63;
  int grp = lane >> 3, l8 = lane & 7;
  int sid = wave*8 + grp;
  const float4 z4 = make_float4(0.f,0.f,0.f,0.f);
  const uint4* xh4 = reinterpret_cast<const uint4*>(xh);   // row = 16 uint4
  const float4* q4 = reinterpret_cast<const float4*>(&qstar[(size_t)b*K1]);
  float4 q0 = q4[2*l8], q1 = q4[2*l8 + 1], q2 = q4[16 + 2*l8], q3 = q4[16 + 2*l8 + 1];

  float m = -INFINITY, d = 0.f;
  float4 ra = z4, rb = z4, rc = z4, rd = z4;

  int j = s + sid;
  uint4 A0, A1, B0, B1;
  {
    int jc0 = (j      < ce) ? j      : jmax;
    int jc1 = (j + 32 < ce) ? j + 32 : jmax;
    const uint4* r0 = xh4 + (size_t)jc0*16;
    const uint4* r1 = xh4 + (size_t)jc1*16;
    A0 = r0[l8]; A1 = r0[8 + l8];
    B0 = r1[l8]; B1 = r1[8 + l8];
  }
  for (; j < ce; j += 32){
    int jn = j + 64;
    int jc = (jn < ce) ? jn : jmax;
    const uint4* rp = xh4 + (size_t)jc*16;
    uint4 C0 = rp[l8], C1 = rp[8 + l8];

    float4 xa, xb, xc, xd;
    h8_to_f_(A0, xa, xb);
    h8_to_f_(A1, xc, xd);
    float e = dot4_(xa, q0) + dot4_(xb, q1) + dot4_(xc, q2) + dot4_(xd, q3);
    e = reduce8_(e);
    if (e > m){
      float corr = __expf(m - e);
      d *= corr;
      ra.x *= corr; ra.y *= corr; ra.z *= corr; ra.w *= corr;
      rb.x *= corr; rb.y *= corr; rb.z *= corr; rb.w *= corr;
      rc.x *= corr; rc.y *= corr; rc.z *= corr; rc.w *= corr;
      rd.x *= corr; rd.y *= corr; rd.z *= corr; rd.w *= corr;
      m = e;
    }
    float p = __expf(e - m);
    d += p;
    ra.x += p*xa.x; ra.y += p*xa.y; ra.z += p*xa.z; ra.w += p*xa.w;
    rb.x += p*xb.x; rb.y += p*xb.y; rb.z += p*xb.z; rb.w += p*xb.w;
    rc.x += p*xc.x; rc.y += p*xc.y; rc.z += p*xc.z; rc.w += p*xc.w;
    rd.x += p*xd.x; rd.y += p*xd.y; rd.z += p*xd.z; rd.w += p*xd.w;
    A0 = B0; A1 = B1;
    B0 = C0; B1 = C1;
  }
  MERGE_STAGE(swz8_)
  MERGE_STAGE(swz16_)
  MERGE_STAGE(SHFL32)

  __shared__ float mbuf[4], dbuf[4];
  __shared__ float rbuf[4][IN_CH];
  if (lane < 8){
    *reinterpret_cast<float4*>(&rbuf[wave][     lane*8    ]) = ra;
    *reinterpret_cast<float4*>(&rbuf[wave][     lane*8 + 4]) = rb;
    *reinterpret_cast<float4*>(&rbuf[wave][64 + lane*8    ]) = rc;
    *reinterpret_cast<float4*>(&rbuf[wave][64 + lane*8 + 4]) = rd;
    if (lane == 0){ mbuf[wave] = m; dbuf[wave] = d; }
  }
  __syncthreads();
  if (tid < IN_CH){
    float M = fmaxf(fmaxf(mbuf[0], mbuf[1]), fmaxf(mbuf[2], mbuf[3]));
    float f0 = (M == -INFINITY) ? 0.f : __expf(mbuf[0] - M);
    float f1 = (M == -INFINITY) ? 0.f : __expf(mbuf[1] - M);
    float f2 = (M == -INFINITY) ? 0.f : __expf(mbuf[2] - M);
    float f3 = (M == -INFINITY) ? 0.f : __expf(mbuf[3] - M);
    float R = rbuf[0][tid]*f0 + rbuf[1][tid]*f1 + rbuf[2][tid]*f2 + rbuf[3][tid]*f3;
    float D = dbuf[0]*f0 + dbuf[1]*f1 + dbuf[2]*f2 + dbuf[3]*f3;
    qstar[(size_t)b*K1 + IN_CH + tid] = (D > 0.f) ? R/D : 0.f;
  }
}

#undef MERGE_STAGE
#undef SHFL32

extern "C" void kernel_launch(void* const* d_in, const int* in_sizes, int n_in,
                              void* d_out, int out_size, void* d_ws, size_t ws_size,
                              hipStream_t stream){
  const float* x     = (const float*)d_in[0];
  const float* w_ih  = (const float*)d_in[1];
  const float* w_hh  = (const float*)d_in[2];
  const float* b_ih  = (const float*)d_in[3];
  const float* b_hh  = (const float*)d_in[4];
  const int*   batch = (const int*)d_in[5];
  int N = in_sizes[0] / IN_CH;
  int B = out_size / K1;
  float* out = (float*)d_out;   // q_star lives here

  __half* xh   = (__half*)d_ws;                 // N*128 halves (fp16 copy of x)
  float*  fb   = (float*)(xh + (size_t)N*IN_CH);
  float* h     = fb;                    // B*128
  float* c     = h + (size_t)B*IN_CH;   // B*128
  float* wTih  = c + (size_t)B*IN_CH;   // 256*512
  float* wThh  = wTih + K1*G4;          // 128*512
  int*   segs  = (int*)(wThh + IN_CH*G4);      // B+1

  prologue_kernel<<<517 + (B*IN_CH + 255)/256, 256, 0, stream>>>(
      w_ih, w_hh, wTih, wThh, batch, N, B, segs, b_ih, b_hh, h, c, out);

  attn_first_kernel<<<B, 256, 0, stream>>>(x, xh, out, segs);
  for (int step = 1; step < 3; ++step){
    lstm_fused_kernel<<<B/8, 512, 0, stream>>>(out, h, c, wTih, wThh, b_ih, b_hh, out);
    attn_half_kernel<<<B, 256, 0, stream>>>(xh, out, segs);
  }
}

// Round 10
// 200.133 us; speedup vs baseline: 1.0703x; 1.0703x over previous
//
#include <hip/hip_runtime.h>
#include <math.h>

#define IN_CH 128
#define G4    512   // 4*IN
#define K1    256   // 2*IN

__device__ __forceinline__ float sigmoidf_(float v){ return 1.f/(1.f + expf(-v)); }

__device__ __forceinline__ float dot4_(float4 a, float4 b){
  return a.x*b.x + a.y*b.y + a.z*b.z + a.w*b.w;
}

// All-reduce-sum over each 32-lane half: 4 pure-DPP stages + 1 ds_swizzle (xor16).
// After xor1,xor2 each quad is uniform, so row_half_mirror/row_mirror act as xor4/xor8.
__device__ __forceinline__ float reduce32_(float v){
  int t;
  t = __builtin_amdgcn_update_dpp(0, __float_as_int(v), 0xB1, 0xF, 0xF, true);   // quad_perm xor1
  v += __int_as_float(t);
  t = __builtin_amdgcn_update_dpp(0, __float_as_int(v), 0x4E, 0xF, 0xF, true);   // quad_perm xor2
  v += __int_as_float(t);
  t = __builtin_amdgcn_update_dpp(0, __float_as_int(v), 0x141, 0xF, 0xF, true);  // row_half_mirror = xor4
  v += __int_as_float(t);
  t = __builtin_amdgcn_update_dpp(0, __float_as_int(v), 0x140, 0xF, 0xF, true);  // row_mirror = xor8
  v += __int_as_float(t);
  t = __builtin_amdgcn_ds_swizzle(__float_as_int(v), 0x401F);                    // lane ^ 16
  return v + __int_as_float(t);
}

// Prologue: transpose weights + segment bounds + step-0 LSTM collapse (bias-only).
__global__ void prologue_kernel(const float* __restrict__ w_ih, const float* __restrict__ w_hh,
                                float* __restrict__ wTih, float* __restrict__ wThh,
                                const int* __restrict__ batch, int N, int B, int* __restrict__ segs,
                                const float* __restrict__ b_ih, const float* __restrict__ b_hh,
                                float* __restrict__ h, float* __restrict__ c, float* __restrict__ qstar){
  int blk = blockIdx.x;
  if (blk < 512){                       // transpose: idx over G4*K1 = 131072
    int idx = blk*256 + threadIdx.x;
    { int g = idx / K1; int k = idx - g*K1; wTih[k*G4 + g] = w_ih[idx]; }
    if (idx < G4*IN_CH){ int g = idx / IN_CH; int k = idx - g*IN_CH; wThh[k*G4 + g] = w_hh[idx]; }
  } else if (blk < 517){                // seg bounds: b in [0, B]
    int b = (blk - 512)*256 + threadIdx.x;
    if (b > B) return;
    if (b == B){ segs[B] = N; return; }
    int lo = 0, hi = N;
    while (lo < hi){ int mid = (lo + hi) >> 1; if (batch[mid] < b) lo = mid + 1; else hi = mid; }
    segs[b] = lo;
  } else {                              // init0: idx over B*IN_CH = 131072
    int idx = (blk - 517)*256 + threadIdx.x;
    if (idx >= B*IN_CH) return;
    int b = idx >> 7, ch = idx & 127;
    float iv = sigmoidf_(b_ih[ch]           + b_hh[ch]);
    float gv = tanhf    (b_ih[2*IN_CH + ch] + b_hh[2*IN_CH + ch]);
    float ov = sigmoidf_(b_ih[3*IN_CH + ch] + b_hh[3*IN_CH + ch]);
    float cv = iv*gv;           // f*c_prev = 0
    float hv = ov*tanhf(cv);
    c[idx] = cv; h[idx] = hv;
    qstar[b*K1 + ch] = hv;
  }
}

// Fused LSTM step (steps 1,2): gates in LDS, then cell update + q-half write.
__global__ __launch_bounds__(512) void lstm_fused_kernel(
    const float* __restrict__ qstar_in, float* __restrict__ h, float* __restrict__ c,
    const float* __restrict__ wTih, const float* __restrict__ wThh,
    const float* __restrict__ b_ih, const float* __restrict__ b_hh,
    float* __restrict__ qstar_out){
  int g    = threadIdx.x;      // 0..511
  int row0 = blockIdx.x*8;
  __shared__ float qs[8][K1];
  __shared__ float hs[8][IN_CH];
  __shared__ float gs[8][G4];
  for (int t = g; t < 8*K1; t += 512){ int r = t >> 8; int k = t & 255; qs[r][k] = qstar_in[(row0+r)*K1 + k]; }
  for (int t = g; t < 8*IN_CH; t += 512){ int r = t >> 7; int k = t & 127; hs[r][k] = h[(row0+r)*IN_CH + k]; }
  __syncthreads();
  float bias = b_ih[g] + b_hh[g];
  float acc[8];
#pragma unroll
  for (int r = 0; r < 8; ++r) acc[r] = bias;
  for (int k4 = 0; k4 < K1/4; ++k4){
    float w0 = wTih[(4*k4+0)*G4 + g];
    float w1 = wTih[(4*k4+1)*G4 + g];
    float w2 = wTih[(4*k4+2)*G4 + g];
    float w3 = wTih[(4*k4+3)*G4 + g];
#pragma unroll
    for (int r = 0; r < 8; ++r){
      float4 q = *reinterpret_cast<const float4*>(&qs[r][4*k4]);
      acc[r] += q.x*w0 + q.y*w1 + q.z*w2 + q.w*w3;
    }
  }
  for (int k4 = 0; k4 < IN_CH/4; ++k4){
    float w0 = wThh[(4*k4+0)*G4 + g];
    float w1 = wThh[(4*k4+1)*G4 + g];
    float w2 = wThh[(4*k4+2)*G4 + g];
    float w3 = wThh[(4*k4+3)*G4 + g];
#pragma unroll
    for (int r = 0; r < 8; ++r){
      float4 hv = *reinterpret_cast<const float4*>(&hs[r][4*k4]);
      acc[r] += hv.x*w0 + hv.y*w1 + hv.z*w2 + hv.w*w3;
    }
  }
#pragma unroll
  for (int r = 0; r < 8; ++r) gs[r][g] = acc[r];
  __syncthreads();
  for (int t = g; t < 8*IN_CH; t += 512){
    int r = t >> 7, ch = t & 127;
    int idx = (row0+r)*IN_CH + ch;
    float iv = sigmoidf_(gs[r][ch]);
    float fv = sigmoidf_(gs[r][IN_CH + ch]);
    float gv = tanhf(gs[r][2*IN_CH + ch]);
    float ov = sigmoidf_(gs[r][3*IN_CH + ch]);
    float cv = fv*c[idx] + iv*gv;
    float hv = ov*tanhf(cv);
    c[idx] = cv; h[idx] = hv;
    qstar_out[(row0+r)*K1 + ch] = hv;
  }
}

// Single-pass online-softmax weighted readout. One block (4 waves) per segment.
// Each wave owns an 8-row (4KB) window per iteration; every load instruction is
// 64 lanes x 16B = 1KB CONTIGUOUS (instr k -> rows {2k,2k+1}, half-wave per row,
// lane&31 = channel quad). 32-lane DPP+swizzle score reduce; single float4
// channel-owned accumulator; deferred-max rescale; depth-2 prefetch with
// 3-phase register rotation (no pointer-swap moves).
__global__ __launch_bounds__(256) void attn_kernel(const float* __restrict__ x,
    float* __restrict__ qstar, const int* __restrict__ segs){
  int b = blockIdx.x;
  int s = segs[b], ce = segs[b+1];
  int jmax = (ce > 0) ? (ce - 1) : 0;   // clamp row (guards empty segments)
  int tid = threadIdx.x;
  int wave = tid >> 6, lane = tid & 63;
  int hh = lane >> 5, l32 = lane & 31;
  const float4* x4 = reinterpret_cast<const float4*>(x);
  const float4* q4 = reinterpret_cast<const float4*>(&qstar[(size_t)b*K1]);
  float4 qv = q4[l32];                  // this lane's 4 channels (both halves same)

  float m = -INFINITY, d = 0.f;
  float4 acc = make_float4(0.f,0.f,0.f,0.f);

  const int WSTR = 32;                  // rows per block-iteration (4 waves x 8)
  int jw = s + wave*8;                  // this wave's current window base

  float4 A0,A1,A2,A3, B0,B1,B2,B3, C0,C1,C2,C3;

#define LOADW(R0,R1,R2,R3,WB_)                                   \
  {                                                              \
    int r0 = min((WB_) + 0 + hh, jmax);                          \
    int r1 = min((WB_) + 2 + hh, jmax);                          \
    int r2 = min((WB_) + 4 + hh, jmax);                          \
    int r3 = min((WB_) + 6 + hh, jmax);                          \
    R0 = x4[(size_t)r0*(IN_CH/4) + l32];                         \
    R1 = x4[(size_t)r1*(IN_CH/4) + l32];                         \
    R2 = x4[(size_t)r2*(IN_CH/4) + l32];                         \
    R3 = x4[(size_t)r3*(IN_CH/4) + l32];                         \
  }

#define COMP(R0,R1,R2,R3,WB_)                                    \
  {                                                              \
    float e0 = dot4_(R0, qv);                                    \
    float e1 = dot4_(R1, qv);                                    \
    float e2 = dot4_(R2, qv);                                    \
    float e3 = dot4_(R3, qv);                                    \
    e0 = reduce32_(e0); e1 = reduce32_(e1);                      \
    e2 = reduce32_(e2); e3 = reduce32_(e3);                      \
    e0 = ((WB_) + 0 + hh < ce) ? e0 : -INFINITY;                 \
    e1 = ((WB_) + 2 + hh < ce) ? e1 : -INFINITY;                 \
    e2 = ((WB_) + 4 + hh < ce) ? e2 : -INFINITY;                 \
    e3 = ((WB_) + 6 + hh < ce) ? e3 : -INFINITY;                 \
    float em = fmaxf(fmaxf(e0,e1), fmaxf(e2,e3));                \
    if (em > m){                                                 \
      float corr = __expf(m - em);                               \
      d *= corr;                                                 \
      acc.x *= corr; acc.y *= corr; acc.z *= corr; acc.w *= corr;\
      m = em;                                                    \
    }                                                            \
    float p0 = (e0 == -INFINITY) ? 0.f : __expf(e0 - m);         \
    float p1 = (e1 == -INFINITY) ? 0.f : __expf(e1 - m);         \
    float p2 = (e2 == -INFINITY) ? 0.f : __expf(e2 - m);         \
    float p3 = (e3 == -INFINITY) ? 0.f : __expf(e3 - m);         \
    d += (p0 + p1) + (p2 + p3);                                  \
    acc.x += p0*R0.x + p1*R1.x + p2*R2.x + p3*R3.x;              \
    acc.y += p0*R0.y + p1*R1.y + p2*R2.y + p3*R3.y;              \
    acc.z += p0*R0.z + p1*R1.z + p2*R2.z + p3*R3.z;              \
    acc.w += p0*R0.w + p1*R1.w + p2*R2.w + p3*R3.w;              \
  }

  LOADW(A0,A1,A2,A3, jw)
  LOADW(B0,B1,B2,B3, jw + WSTR)
  for (;;){
    if (jw >= ce) break;
    LOADW(C0,C1,C2,C3, jw + 2*WSTR)
    COMP (A0,A1,A2,A3, jw)
    jw += WSTR;
    if (jw >= ce) break;
    LOADW(A0,A1,A2,A3, jw + 2*WSTR)
    COMP (B0,B1,B2,B3, jw)
    jw += WSTR;
    if (jw >= ce) break;
    LOADW(B0,B1,B2,B3, jw + 2*WSTR)
    COMP (C0,C1,C2,C3, jw)
    jw += WSTR;
  }
#undef LOADW
#undef COMP

  // merge the two halves of the wave (same channels, lane^32)
  {
    float mo = __shfl_xor(m, 32), dd = __shfl_xor(d, 32);
    float ox = __shfl_xor(acc.x, 32), oy = __shfl_xor(acc.y, 32);
    float oz = __shfl_xor(acc.z, 32), ow = __shfl_xor(acc.w, 32);
    float mn = fmaxf(m, mo);
    float c1 = (mn == -INFINITY) ? 0.f : __expf(m - mn);
    float c2 = (mn == -INFINITY) ? 0.f : __expf(mo - mn);
    d = d*c1 + dd*c2;
    acc.x = acc.x*c1 + ox*c2; acc.y = acc.y*c1 + oy*c2;
    acc.z = acc.z*c1 + oz*c2; acc.w = acc.w*c1 + ow*c2;
    m = mn;
  }
  __shared__ float mbuf[4], dbuf[4];
  __shared__ float rbuf[4][IN_CH];
  if (lane < 32){
    *reinterpret_cast<float4*>(&rbuf[wave][l32*4]) = acc;
    if (l32 == 0){ mbuf[wave] = m; dbuf[wave] = d; }
  }
  __syncthreads();
  if (tid < IN_CH){
    float M = fmaxf(fmaxf(mbuf[0], mbuf[1]), fmaxf(mbuf[2], mbuf[3]));
    float f0 = (M == -INFINITY) ? 0.f : __expf(mbuf[0] - M);
    float f1 = (M == -INFINITY) ? 0.f : __expf(mbuf[1] - M);
    float f2 = (M == -INFINITY) ? 0.f : __expf(mbuf[2] - M);
    float f3 = (M == -INFINITY) ? 0.f : __expf(mbuf[3] - M);
    float R = rbuf[0][tid]*f0 + rbuf[1][tid]*f1 + rbuf[2][tid]*f2 + rbuf[3][tid]*f3;
    float D = dbuf[0]*f0 + dbuf[1]*f1 + dbuf[2]*f2 + dbuf[3]*f3;
    qstar[(size_t)b*K1 + IN_CH + tid] = (D > 0.f) ? R/D : 0.f;
  }
}

extern "C" void kernel_launch(void* const* d_in, const int* in_sizes, int n_in,
                              void* d_out, int out_size, void* d_ws, size_t ws_size,
                              hipStream_t stream){
  const float* x     = (const float*)d_in[0];
  const float* w_ih  = (const float*)d_in[1];
  const float* w_hh  = (const float*)d_in[2];
  const float* b_ih  = (const float*)d_in[3];
  const float* b_hh  = (const float*)d_in[4];
  const int*   batch = (const int*)d_in[5];
  int N = in_sizes[0] / IN_CH;
  int B = out_size / K1;
  float* out = (float*)d_out;   // q_star lives here

  float* ws    = (float*)d_ws;
  float* h     = ws;                    // B*128
  float* c     = h + (size_t)B*IN_CH;   // B*128
  float* wTih  = c + (size_t)B*IN_CH;   // 256*512
  float* wThh  = wTih + K1*G4;          // 128*512
  int*   segs  = (int*)(wThh + IN_CH*G4);      // B+1

  prologue_kernel<<<517 + (B*IN_CH + 255)/256, 256, 0, stream>>>(
      w_ih, w_hh, wTih, wThh, batch, N, B, segs, b_ih, b_hh, h, c, out);

  attn_kernel<<<B, 256, 0, stream>>>(x, out, segs);
  for (int step = 1; step < 3; ++step){
    lstm_fused_kernel<<<B/8, 512, 0, stream>>>(out, h, c, wTih, wThh, b_ih, b_hh, out);
    attn_kernel<<<B, 256, 0, stream>>>(x, out, segs);
  }
}